// Round 4
// baseline (32625.565 us; speedup 1.0000x reference)
//
#include <hip/hip_runtime.h>
#include <stdint.h>

typedef unsigned int uint;

#define T_SEQ 512
#define D_IN 64
#define H_ 256
#define KTOT 320      // D_IN + H_
#define NTOT 1024     // 4*H_
#define MID_ 64
#define ACT_ 3
#define B_TOT 1024
#define ROWS 16       // batch rows per block
#define NBLK 64
#define THREADS 512   // 8 waves
#define KB 10         // K blocks of 32 (320/32)
#define APAD 328      // padded A-row stride (elements)
#define WP_ELEMS 40960                  // uint4 per weight plane (64 nt * 10 kb * 64)
#define WP_BYTES (WP_ELEMS * 16)        // 640 KB per plane
#define WP0_OFF 1024
#define WP1_OFF (WP0_OFF + WP_BYTES)
#define WP2_OFF (WP1_OFF + WP_BYTES)

typedef __attribute__((ext_vector_type(8))) short short8;
typedef __attribute__((ext_vector_type(4))) float floatx4;

__device__ inline float bf2f(unsigned short s) {
  union { uint u; float f; } v; v.u = ((uint)s) << 16; return v.f;
}
__device__ inline unsigned short f2bf(float f) {
  union { float f; uint u; } v; v.f = f;
  uint r = v.u + 0x7FFFu + ((v.u >> 16) & 1u);   // RNE
  return (unsigned short)(r >> 16);
}
union U4S8 { uint4 u; short8 s; };
__device__ inline short8 u4s8(uint4 v) { U4S8 t; t.u = v; return t.s; }

// load input element idx as float, from fp32 or bf16 storage
__device__ inline float ldin(const void* p, int idx, int isf) {
  return isf ? ((const float*)p)[idx] : bf2f(((const unsigned short*)p)[idx]);
}

// 3-digit bf16 split: f = d0 + d1 + d2 + O(2^-27 |f|); residual subs are exact
__device__ inline void split3(float f, unsigned short& d0, unsigned short& d1,
                              unsigned short& d2) {
  d0 = f2bf(f);
  float r1 = f - bf2f(d0);
  d1 = f2bf(r1);
  float r2 = r1 - bf2f(d1);
  d2 = f2bf(r2);
}

// ---- dtype detector: fp32 storage => low halves of floats are mantissa junk
__global__ void detect_dtype(const unsigned short* __restrict__ x,
                             int* __restrict__ flag) {
  if (blockIdx.x == 0 && threadIdx.x == 0) {
    int f = 0;
    for (int i = 0; i < 256; ++i) {
      float v = bf2f(x[i]);
      if (!(fabsf(v) < 1e10f)) f = 1;   // catches huge, inf, NaN
    }
    *flag = f;
  }
}

// Repack Wc (KTOT x NTOT, row-major) into 3 bf16-digit MFMA B-fragment planes:
// frag index = nt*KB + kb ; element = frag*64 + lane ; lane holds
// B[k = kb*32 + (lane>>4)*8 + j][n = nt*16 + (lane&15)], j=0..7 packed in 16B.
__global__ void repack_wc(const void* __restrict__ Wc,
                          uint4* __restrict__ W0, uint4* __restrict__ W1,
                          uint4* __restrict__ W2,
                          const int* __restrict__ flag) {
  int tid = blockIdx.x * blockDim.x + threadIdx.x;  // 40960 threads
  int lane = tid & 63;
  int frag = tid >> 6;                              // 0..639
  int nt = frag / KB;
  int kb = frag - nt * KB;
  int n = nt * 16 + (lane & 15);
  int k0 = kb * 32 + (lane >> 4) * 8;
  int isf = *flag;
  unsigned short e0[8], e1[8], e2[8];
#pragma unroll
  for (int j = 0; j < 8; ++j) {
    size_t idx = (size_t)(k0 + j) * NTOT + n;
    float w = isf ? ((const float*)Wc)[idx] : bf2f(((const unsigned short*)Wc)[idx]);
    split3(w, e0[j], e1[j], e2[j]);
  }
  uint4 o0, o1, o2;
  o0.x = (uint)e0[0] | ((uint)e0[1] << 16);
  o0.y = (uint)e0[2] | ((uint)e0[3] << 16);
  o0.z = (uint)e0[4] | ((uint)e0[5] << 16);
  o0.w = (uint)e0[6] | ((uint)e0[7] << 16);
  o1.x = (uint)e1[0] | ((uint)e1[1] << 16);
  o1.y = (uint)e1[2] | ((uint)e1[3] << 16);
  o1.z = (uint)e1[4] | ((uint)e1[5] << 16);
  o1.w = (uint)e1[6] | ((uint)e1[7] << 16);
  o2.x = (uint)e2[0] | ((uint)e2[1] << 16);
  o2.y = (uint)e2[2] | ((uint)e2[3] << 16);
  o2.z = (uint)e2[4] | ((uint)e2[5] << 16);
  o2.w = (uint)e2[6] | ((uint)e2[7] << 16);
  W0[tid] = o0;
  W1[tid] = o1;
  W2[tid] = o2;
}

__global__ __launch_bounds__(THREADS, 2) void xlstm_main(
    const void* __restrict__ xg,
    const void* __restrict__ bc,
    const uint4* __restrict__ W0, const uint4* __restrict__ W1,
    const uint4* __restrict__ W2,
    const void* __restrict__ Wa1, const void* __restrict__ ba1,
    const void* __restrict__ Wa2, const void* __restrict__ ba2,
    const void* __restrict__ Wv1, const void* __restrict__ bv1,
    const void* __restrict__ Wv2, const void* __restrict__ bv2,
    void* __restrict__ outv,
    const int* __restrict__ flagp)
{
  __shared__ short A0[2][ROWS][APAD];            // digit-0 plane [xt | h], dbuf
  __shared__ short A1[2][ROWS][APAD];            // digit-1 plane
  __shared__ short A2[2][ROWS][APAD];            // digit-2 plane
  __shared__ float h32[ROWS][H_ + 4];            // final h in fp32 for the heads
  __shared__ float mida[ROWS][MID_ + 2];
  __shared__ float midv[ROWS][MID_ + 2];
  __shared__ float lgts[ROWS][4];

  const int tid = threadIdx.x;
  const int lane = tid & 63;
  const int wave = tid >> 6;                     // 0..7
  const int b0 = blockIdx.x * ROWS;
  const int isf = *flagp;                        // uniform

  // zero h-section of all planes of buffer 0 (h0 = 0)
  {
    int r = tid >> 5;                            // 0..15
    int c0 = 64 + (tid & 31) * 8;                // 64..312
    *(uint4*)&A0[0][r][c0] = make_uint4(0u, 0u, 0u, 0u);
    *(uint4*)&A1[0][r][c0] = make_uint4(0u, 0u, 0u, 0u);
    *(uint4*)&A2[0][r][c0] = make_uint4(0u, 0u, 0u, 0u);
  }

  // x staging: each thread owns 2 consecutive x elements of one row per step
  const int xr = tid >> 5;                       // row 0..15
  const int xc = tid & 31;                       // elem-pair col 0..31
  const uint*  xu_base = (const uint*)xg + ((size_t)(b0 + xr) * T_SEQ) * 32 + xc;
  const float* xf_base = (const float*)xg + ((size_t)(b0 + xr) * T_SEQ) * 64 + xc * 2;
  uint x0 = 0, x1 = 0, x2 = 0;
  {
    float a, b;
    if (isf) { float2 v = *(const float2*)xf_base; a = v.x; b = v.y; }
    else     { uint u = xu_base[0]; a = bf2f((unsigned short)u);
               b = bf2f((unsigned short)(u >> 16)); }
    unsigned short a0,a1,a2,b0_,b1_,b2_;
    split3(a, a0, a1, a2); split3(b, b0_, b1_, b2_);
    x0 = (uint)a0 | ((uint)b0_ << 16);
    x1 = (uint)a1 | ((uint)b1_ << 16);
    x2 = (uint)a2 | ((uint)b2_ << 16);
  }

  const int l15 = lane & 15;
  const int quad = lane >> 4;
  const int crow = quad * 4;                     // C-layout row base
  const int u0 = wave * 32 + l15;                // hidden unit, tile pair 0
  const int u1 = u0 + 16;                        // tile pair 1

  const float bi0 = ldin(bc, u0, isf),          bi1 = ldin(bc, u1, isf);
  const float bf0 = ldin(bc, H_ + u0, isf),     bf1 = ldin(bc, H_ + u1, isf);
  const float bo0 = ldin(bc, 2*H_ + u0, isf),   bo1 = ldin(bc, 2*H_ + u1, isf);
  const float bz0 = ldin(bc, 3*H_ + u0, isf),   bz1 = ldin(bc, 3*H_ + u1, isf);

  float cst[2][4], nst[2][4];
#pragma unroll
  for (int tp = 0; tp < 2; ++tp)
#pragma unroll
    for (int r = 0; r < 4; ++r) { cst[tp][r] = 0.f; nst[tp][r] = 1.f; }

  for (int t = 0; t < T_SEQ; ++t) {
    const int cur = t & 1, nxt = cur ^ 1;
    *(uint*)&A0[cur][xr][xc * 2] = x0;           // write x(t) digits
    *(uint*)&A1[cur][xr][xc * 2] = x1;
    *(uint*)&A2[cur][xr][xc * 2] = x2;
    __syncthreads();
    // prefetch x(t+1) AFTER the barrier so its latency hides under the GEMM
    if (t + 1 < T_SEQ) {
      float a, b;
      if (isf) { float2 v = *(const float2*)(xf_base + (size_t)(t + 1) * 64);
                 a = v.x; b = v.y; }
      else     { uint u = xu_base[(size_t)(t + 1) * 32]; a = bf2f((unsigned short)u);
                 b = bf2f((unsigned short)(u >> 16)); }
      unsigned short a0,a1,a2,b0_,b1_,b2_;
      split3(a, a0, a1, a2); split3(b, b0_, b1_, b2_);
      x0 = (uint)a0 | ((uint)b0_ << 16);
      x1 = (uint)a1 | ((uint)b1_ << 16);
      x2 = (uint)a2 | ((uint)b2_ << 16);
    }

    // A-fragments (3 digit planes): A[m = l15][k = kb*32 + quad*8 + j]
    short8 fa0[KB], fa1[KB], fa2[KB];
#pragma unroll
    for (int kb = 0; kb < KB; ++kb) {
      fa0[kb] = *(const short8*)&A0[cur][l15][kb * 32 + quad * 8];
      fa1[kb] = *(const short8*)&A1[cur][l15][kb * 32 + quad * 8];
      fa2[kb] = *(const short8*)&A2[cur][l15][kb * 32 + quad * 8];
    }

    // gates GEMM, 3-digit split: keep products with digit-weight i+j <= 2:
    //   a0w0 + a1w0 + a0w1 + a2w0 + a1w1 + a0w2   (error ~ fp32 GEMM rounding)
    floatx4 acc[4][2];
#pragma unroll
    for (int g = 0; g < 4; ++g) {
#pragma unroll
      for (int tp = 0; tp < 2; ++tp) {
        const size_t toff = (size_t)((g * 16 + wave * 2 + tp) * KB) * 64 + lane;
        const uint4* bp0 = W0 + toff;
        const uint4* bp1 = W1 + toff;
        const uint4* bp2 = W2 + toff;
        floatx4 a = {0.f, 0.f, 0.f, 0.f};
#pragma unroll
        for (int kb = 0; kb < KB; ++kb) {
          short8 w0 = u4s8(bp0[kb * 64]);
          a = __builtin_amdgcn_mfma_f32_16x16x32_bf16(fa0[kb], w0, a, 0, 0, 0);
          a = __builtin_amdgcn_mfma_f32_16x16x32_bf16(fa1[kb], w0, a, 0, 0, 0);
          a = __builtin_amdgcn_mfma_f32_16x16x32_bf16(fa2[kb], w0, a, 0, 0, 0);
          short8 w1 = u4s8(bp1[kb * 64]);
          a = __builtin_amdgcn_mfma_f32_16x16x32_bf16(fa0[kb], w1, a, 0, 0, 0);
          a = __builtin_amdgcn_mfma_f32_16x16x32_bf16(fa1[kb], w1, a, 0, 0, 0);
          short8 w2 = u4s8(bp2[kb * 64]);
          a = __builtin_amdgcn_mfma_f32_16x16x32_bf16(fa0[kb], w2, a, 0, 0, 0);
        }
        acc[g][tp] = a;
      }
    }

    // sLSTM update, all in registers (lane owns 8 (row,unit) pairs)
#pragma unroll
    for (int tp = 0; tp < 2; ++tp) {
      const float bi = tp ? bi1 : bi0;
      const float bf = tp ? bf1 : bf0;
      const float bo = tp ? bo1 : bo0;
      const float bz = tp ? bz1 : bz0;
      const int unit = tp ? u1 : u0;
#pragma unroll
      for (int r = 0; r < 4; ++r) {
        float iv = __expf(fminf(fmaxf(acc[0][tp][r] + bi, -5.f), 5.f));
        float fv = __expf(fminf(fmaxf(acc[1][tp][r] + bf, -5.f), 5.f));
        float ov = acc[2][tp][r] + bo;
        float zv = acc[3][tp][r] + bz;
        float e2z = __expf(2.f * zv);
        float tz = 1.f - 2.f / (e2z + 1.f);      // tanh, exact div
        float cv = fv * cst[tp][r] + iv * tz;
        cv = fminf(fmaxf(cv, -1e6f), 1e6f);
        float nv = fv * nst[tp][r] + iv;
        nv = fminf(fmaxf(nv, 1e-6f), 1e6f);
        cst[tp][r] = cv; nst[tp][r] = nv;
        float sg = 1.f / (1.f + __expf(-ov));    // sigmoid, exact div
        float hv = sg * (cv / nv);
        if (!(fabsf(hv) < 1e37f)) hv = 0.f;      // nan_to_num(nan/±inf -> 0)
        unsigned short d0, d1, d2;
        split3(hv, d0, d1, d2);
        A0[nxt][crow + r][64 + unit] = (short)d0;
        A1[nxt][crow + r][64 + unit] = (short)d1;
        A2[nxt][crow + r][64 + unit] = (short)d2;
        if (t == T_SEQ - 1) h32[crow + r][unit] = hv;
      }
    }
  }
  __syncthreads();

  // ---- heads (fp32 VALU, one-time) ----
#pragma unroll
  for (int it = 0; it < 2; ++it) {
    int idx = tid + it * THREADS;                // 0..1023
    int r = idx >> 6, m = idx & 63;
    float sa = ldin(ba1, m, isf);
    float sv = ldin(bv1, m, isf);
    for (int k = 0; k < H_; ++k) {
      float hv = h32[r][k];
      sa += hv * ldin(Wa1, k * MID_ + m, isf);
      sv += hv * ldin(Wv1, k * MID_ + m, isf);
    }
    mida[r][m] = fmaxf(sa, 0.f);
    midv[r][m] = fmaxf(sv, 0.f);
  }
  __syncthreads();
  if (tid < ROWS * 4) {
    int r = tid >> 2, j = tid & 3;
    if (j < 3) {
      float s = ldin(ba2, j, isf);
      for (int m = 0; m < MID_; ++m) s += mida[r][m] * ldin(Wa2, m * ACT_ + j, isf);
      lgts[r][j] = s;
    } else {
      float s = ldin(bv2, 0, isf);
      for (int m = 0; m < MID_; ++m) s += midv[r][m] * ldin(Wv2, m, isf);
      int oi = 3 * B_TOT + b0 + r;               // value output
      if (isf) ((float*)outv)[oi] = s; else ((unsigned short*)outv)[oi] = f2bf(s);
    }
  }
  __syncthreads();
  if (tid < ROWS) {
    float l0 = lgts[tid][0], l1 = lgts[tid][1], l2 = lgts[tid][2];
    float mx = fmaxf(l0, fmaxf(l1, l2));
    float e0 = __expf(l0 - mx), e1 = __expf(l1 - mx), e2 = __expf(l2 - mx);
    float inv = 1.f / (e0 + e1 + e2);
    int oi = (b0 + tid) * 3;
    if (isf) {
      ((float*)outv)[oi + 0] = e0 * inv;
      ((float*)outv)[oi + 1] = e1 * inv;
      ((float*)outv)[oi + 2] = e2 * inv;
    } else {
      ((unsigned short*)outv)[oi + 0] = f2bf(e0 * inv);
      ((unsigned short*)outv)[oi + 1] = f2bf(e1 * inv);
      ((unsigned short*)outv)[oi + 2] = f2bf(e2 * inv);
    }
  }
}

extern "C" void kernel_launch(void* const* d_in, const int* in_sizes, int n_in,
                              void* d_out, int out_size, void* d_ws, size_t ws_size,
                              hipStream_t stream) {
  const void* x   = d_in[0];
  const void* Wc  = d_in[1];
  const void* bc  = d_in[2];
  const void* Wa1 = d_in[3];
  const void* ba1 = d_in[4];
  const void* Wa2 = d_in[5];
  const void* ba2 = d_in[6];
  const void* Wv1 = d_in[7];
  const void* bv1 = d_in[8];
  const void* Wv2 = d_in[9];
  const void* bv2 = d_in[10];

  int*   flag = (int*)d_ws;
  uint4* W0p  = (uint4*)((char*)d_ws + WP0_OFF);   // 640 KB digit-0 plane
  uint4* W1p  = (uint4*)((char*)d_ws + WP1_OFF);   // 640 KB digit-1 plane
  uint4* W2p  = (uint4*)((char*)d_ws + WP2_OFF);   // 640 KB digit-2 plane

  detect_dtype<<<1, 64, 0, stream>>>((const unsigned short*)x, flag);
  repack_wc<<<160, 256, 0, stream>>>(Wc, W0p, W1p, W2p, flag);
  xlstm_main<<<NBLK, THREADS, 0, stream>>>(x, bc, W0p, W1p, W2p,
                                           Wa1, ba1, Wa2, ba2,
                                           Wv1, bv1, Wv2, bv2, d_out, flag);
}

// Round 5
// 18440.498 us; speedup vs baseline: 1.7692x; 1.7692x over previous
//
#include <hip/hip_runtime.h>
#include <stdint.h>

typedef unsigned int uint;

#define T_SEQ 512
#define D_IN 64
#define H_ 256
#define KTOT 320      // D_IN + H_
#define NTOT 1024     // 4*H_
#define MID_ 64
#define ACT_ 3
#define B_TOT 1024
#define ROWS 16       // batch rows per block
#define NBLK 64
#define THREADS 512   // 8 waves
#define KB 10         // K blocks of 32 (320/32)
#define APAD 328      // padded A-row stride (elements)
#define WP_ELEMS 40960                  // uint4 per weight plane (64 nt * 10 kb * 64)
#define WP_BYTES (WP_ELEMS * 16)        // 640 KB per plane
#define WP0_OFF 1024
#define WP1_OFF (WP0_OFF + WP_BYTES)
#define INV4096 2.44140625e-4f          // 2^-12

typedef _Float16 half_t;
typedef __attribute__((ext_vector_type(8))) _Float16 half8;
typedef __attribute__((ext_vector_type(4))) float floatx4;

__device__ inline float bf2f(unsigned short s) {
  union { uint u; float f; } v; v.u = ((uint)s) << 16; return v.f;
}
union UHU { half_t h; unsigned short u; };
__device__ inline unsigned short h2u(half_t h) { UHU v; v.h = h; return v.u; }
union U4H8 { uint4 u; half8 h; };
__device__ inline half8 u4h8(uint4 v) { U4H8 t; t.u = v; return t.h; }

// load input element idx as float, from fp32 or bf16 storage
__device__ inline float ldin(const void* p, int idx, int isf) {
  return isf ? ((const float*)p)[idx] : bf2f(((const unsigned short*)p)[idx]);
}

// 2-digit fp16 split with scaled residual: f ≈ d0 + d1*2^-12, rel err ~2^-22.
// d1 is stored PRE-SCALED by 2^12 so it is a normal fp16 (MFMA may flush
// subnormal inputs); products using d1 are accumulated separately and the
// final sum applies the 2^-12 weight.
__device__ inline void split2h(float f, half_t& d0, half_t& d1) {
  d0 = (half_t)f;                       // RNE
  float r = f - (float)d0;              // exact in fp32
  d1 = (half_t)(r * 4096.0f);           // exact scale; RNE round
}

// ---- dtype detector: fp32 storage => low halves of floats are mantissa junk
__global__ void detect_dtype(const unsigned short* __restrict__ x,
                             int* __restrict__ flag) {
  if (blockIdx.x == 0 && threadIdx.x == 0) {
    int f = 0;
    for (int i = 0; i < 256; ++i) {
      float v = bf2f(x[i]);
      if (!(fabsf(v) < 1e10f)) f = 1;   // catches huge, inf, NaN
    }
    *flag = f;
  }
}

// Repack Wc (KTOT x NTOT, row-major) into 2 fp16-digit MFMA B-fragment planes:
// frag index = nt*KB + kb ; element = frag*64 + lane ; lane holds
// B[k = kb*32 + (lane>>4)*8 + j][n = nt*16 + (lane&15)], j=0..7 packed in 16B.
__global__ void repack_wc(const void* __restrict__ Wc,
                          uint4* __restrict__ W0, uint4* __restrict__ W1,
                          const int* __restrict__ flag) {
  int tid = blockIdx.x * blockDim.x + threadIdx.x;  // 40960 threads
  int lane = tid & 63;
  int frag = tid >> 6;                              // 0..639
  int nt = frag / KB;
  int kb = frag - nt * KB;
  int n = nt * 16 + (lane & 15);
  int k0 = kb * 32 + (lane >> 4) * 8;
  int isf = *flag;
  unsigned short e0[8], e1[8];
#pragma unroll
  for (int j = 0; j < 8; ++j) {
    size_t idx = (size_t)(k0 + j) * NTOT + n;
    float w = isf ? ((const float*)Wc)[idx] : bf2f(((const unsigned short*)Wc)[idx]);
    half_t d0, d1;
    split2h(w, d0, d1);
    e0[j] = h2u(d0);
    e1[j] = h2u(d1);
  }
  uint4 o0, o1;
  o0.x = (uint)e0[0] | ((uint)e0[1] << 16);
  o0.y = (uint)e0[2] | ((uint)e0[3] << 16);
  o0.z = (uint)e0[4] | ((uint)e0[5] << 16);
  o0.w = (uint)e0[6] | ((uint)e0[7] << 16);
  o1.x = (uint)e1[0] | ((uint)e1[1] << 16);
  o1.y = (uint)e1[2] | ((uint)e1[3] << 16);
  o1.z = (uint)e1[4] | ((uint)e1[5] << 16);
  o1.w = (uint)e1[6] | ((uint)e1[7] << 16);
  W0[tid] = o0;
  W1[tid] = o1;
}

__global__ __launch_bounds__(THREADS, 2) void xlstm_main(
    const void* __restrict__ xg,
    const void* __restrict__ bc,
    const uint4* __restrict__ W0, const uint4* __restrict__ W1,
    const void* __restrict__ Wa1, const void* __restrict__ ba1,
    const void* __restrict__ Wa2, const void* __restrict__ ba2,
    const void* __restrict__ Wv1, const void* __restrict__ bv1,
    const void* __restrict__ Wv2, const void* __restrict__ bv2,
    void* __restrict__ outv,
    const int* __restrict__ flagp)
{
  __shared__ unsigned short A0[2][ROWS][APAD];   // digit-0 plane [xt | h], dbuf
  __shared__ unsigned short A1[2][ROWS][APAD];   // digit-1 plane (scaled 2^12)
  __shared__ float h32[ROWS][H_ + 4];            // final h in fp32 for the heads
  __shared__ float mida[ROWS][MID_ + 2];
  __shared__ float midv[ROWS][MID_ + 2];
  __shared__ float lgts[ROWS][4];

  const int tid = threadIdx.x;
  const int lane = tid & 63;
  const int wave = tid >> 6;                     // 0..7
  const int b0 = blockIdx.x * ROWS;
  const int isf = *flagp;                        // uniform

  // zero h-section of both planes of buffer 0 (h0 = 0)
  {
    int r = tid >> 5;                            // 0..15
    int c0 = 64 + (tid & 31) * 8;                // 64..312
    *(uint4*)&A0[0][r][c0] = make_uint4(0u, 0u, 0u, 0u);
    *(uint4*)&A1[0][r][c0] = make_uint4(0u, 0u, 0u, 0u);
  }

  // x staging: each thread owns 2 consecutive x elements of one row per step
  const int xr = tid >> 5;                       // row 0..15
  const int xc = tid & 31;                       // elem-pair col 0..31
  const uint*  xu_base = (const uint*)xg + ((size_t)(b0 + xr) * T_SEQ) * 32 + xc;
  const float* xf_base = (const float*)xg + ((size_t)(b0 + xr) * T_SEQ) * 64 + xc * 2;
  uint x0 = 0, x1 = 0;
  {
    float a, b;
    if (isf) { float2 v = *(const float2*)xf_base; a = v.x; b = v.y; }
    else     { uint u = xu_base[0]; a = bf2f((unsigned short)u);
               b = bf2f((unsigned short)(u >> 16)); }
    half_t a0, a1, b0h, b1h;
    split2h(a, a0, a1); split2h(b, b0h, b1h);
    x0 = (uint)h2u(a0) | ((uint)h2u(b0h) << 16);
    x1 = (uint)h2u(a1) | ((uint)h2u(b1h) << 16);
  }

  const int l15 = lane & 15;
  const int quad = lane >> 4;
  const int crow = quad * 4;                     // C-layout row base
  const int u0 = wave * 32 + l15;                // hidden unit, tile pair 0
  const int u1 = u0 + 16;                        // tile pair 1

  const float bi0 = ldin(bc, u0, isf),          bi1 = ldin(bc, u1, isf);
  const float bf0 = ldin(bc, H_ + u0, isf),     bf1 = ldin(bc, H_ + u1, isf);
  const float bo0 = ldin(bc, 2*H_ + u0, isf),   bo1 = ldin(bc, 2*H_ + u1, isf);
  const float bz0 = ldin(bc, 3*H_ + u0, isf),   bz1 = ldin(bc, 3*H_ + u1, isf);

  float cst[2][4], nst[2][4];
#pragma unroll
  for (int tp = 0; tp < 2; ++tp)
#pragma unroll
    for (int r = 0; r < 4; ++r) { cst[tp][r] = 0.f; nst[tp][r] = 1.f; }

  for (int t = 0; t < T_SEQ; ++t) {
    const int cur = t & 1, nxt = cur ^ 1;
    *(uint*)&A0[cur][xr][xc * 2] = x0;           // write x(t) digits
    *(uint*)&A1[cur][xr][xc * 2] = x1;
    __syncthreads();
    // prefetch x(t+1) AFTER the barrier so its latency hides under the GEMM
    if (t + 1 < T_SEQ) {
      float a, b;
      if (isf) { float2 v = *(const float2*)(xf_base + (size_t)(t + 1) * 64);
                 a = v.x; b = v.y; }
      else     { uint u = xu_base[(size_t)(t + 1) * 32]; a = bf2f((unsigned short)u);
                 b = bf2f((unsigned short)(u >> 16)); }
      half_t a0, a1, b0h, b1h;
      split2h(a, a0, a1); split2h(b, b0h, b1h);
      x0 = (uint)h2u(a0) | ((uint)h2u(b0h) << 16);
      x1 = (uint)h2u(a1) | ((uint)h2u(b1h) << 16);
    }

    // A-fragments (2 digit planes): A[m = l15][k = kb*32 + quad*8 + j]
    half8 fa0[KB], fa1[KB];
#pragma unroll
    for (int kb = 0; kb < KB; ++kb) {
      fa0[kb] = u4h8(*(const uint4*)&A0[cur][l15][kb * 32 + quad * 8]);
      fa1[kb] = u4h8(*(const uint4*)&A1[cur][l15][kb * 32 + quad * 8]);
    }

    // gates GEMM, 2-digit fp16 split with scaled-residual planes:
    //   gate = (a0·w0) + 2^-12 · (a0·w1' + a1'·w0)     [a1'w1' ~2^-24, dropped]
    // wave owns tiles nt = g*16 + wave*2 + {0,1} (i/f/o/z co-located)
    floatx4 accA[4][2], accB[4][2];
#pragma unroll
    for (int g = 0; g < 4; ++g) {
#pragma unroll
      for (int tp = 0; tp < 2; ++tp) {
        const size_t toff = (size_t)((g * 16 + wave * 2 + tp) * KB) * 64 + lane;
        const uint4* bp0 = W0 + toff;
        const uint4* bp1 = W1 + toff;
        floatx4 a = {0.f, 0.f, 0.f, 0.f};
        floatx4 b = {0.f, 0.f, 0.f, 0.f};
#pragma unroll
        for (int kb = 0; kb < KB; ++kb) {
          half8 w0 = u4h8(bp0[kb * 64]);
          a = __builtin_amdgcn_mfma_f32_16x16x32_f16(fa0[kb], w0, a, 0, 0, 0);
          b = __builtin_amdgcn_mfma_f32_16x16x32_f16(fa1[kb], w0, b, 0, 0, 0);
          half8 w1 = u4h8(bp1[kb * 64]);
          b = __builtin_amdgcn_mfma_f32_16x16x32_f16(fa0[kb], w1, b, 0, 0, 0);
        }
        accA[g][tp] = a;
        accB[g][tp] = b;
      }
    }

    // sLSTM update, all in registers (lane owns 8 (row,unit) pairs)
#pragma unroll
    for (int tp = 0; tp < 2; ++tp) {
      const float bi = tp ? bi1 : bi0;
      const float bf = tp ? bf1 : bf0;
      const float bo = tp ? bo1 : bo0;
      const float bz = tp ? bz1 : bz0;
      const int unit = tp ? u1 : u0;
#pragma unroll
      for (int r = 0; r < 4; ++r) {
        float gi = accA[0][tp][r] + accB[0][tp][r] * INV4096 + bi;
        float gf = accA[1][tp][r] + accB[1][tp][r] * INV4096 + bf;
        float ov = accA[2][tp][r] + accB[2][tp][r] * INV4096 + bo;
        float zv = accA[3][tp][r] + accB[3][tp][r] * INV4096 + bz;
        float iv = __expf(fminf(fmaxf(gi, -5.f), 5.f));
        float fv = __expf(fminf(fmaxf(gf, -5.f), 5.f));
        float e2z = __expf(2.f * zv);
        float tz = 1.f - 2.f / (e2z + 1.f);      // tanh, exact div
        float cv = fv * cst[tp][r] + iv * tz;
        cv = fminf(fmaxf(cv, -1e6f), 1e6f);
        float nv = fv * nst[tp][r] + iv;
        nv = fminf(fmaxf(nv, 1e-6f), 1e6f);
        cst[tp][r] = cv; nst[tp][r] = nv;
        float sg = 1.f / (1.f + __expf(-ov));    // sigmoid, exact div
        float hv = sg * (cv / nv);
        if (!(fabsf(hv) < 1e37f)) hv = 0.f;      // nan_to_num(nan/±inf -> 0)
        half_t d0, d1;
        split2h(hv, d0, d1);
        A0[nxt][crow + r][64 + unit] = h2u(d0);
        A1[nxt][crow + r][64 + unit] = h2u(d1);
        if (t == T_SEQ - 1) h32[crow + r][unit] = hv;
      }
    }
  }
  __syncthreads();

  // ---- heads (fp32 VALU, one-time) ----
#pragma unroll
  for (int it = 0; it < 2; ++it) {
    int idx = tid + it * THREADS;                // 0..1023
    int r = idx >> 6, m = idx & 63;
    float sa = ldin(ba1, m, isf);
    float sv = ldin(bv1, m, isf);
    for (int k = 0; k < H_; ++k) {
      float hv = h32[r][k];
      sa += hv * ldin(Wa1, k * MID_ + m, isf);
      sv += hv * ldin(Wv1, k * MID_ + m, isf);
    }
    mida[r][m] = fmaxf(sa, 0.f);
    midv[r][m] = fmaxf(sv, 0.f);
  }
  __syncthreads();
  if (tid < ROWS * 4) {
    int r = tid >> 2, j = tid & 3;
    if (j < 3) {
      float s = ldin(ba2, j, isf);
      for (int m = 0; m < MID_; ++m) s += mida[r][m] * ldin(Wa2, m * ACT_ + j, isf);
      lgts[r][j] = s;
    } else {
      float s = ldin(bv2, 0, isf);
      for (int m = 0; m < MID_; ++m) s += midv[r][m] * ldin(Wv2, m, isf);
      int oi = 3 * B_TOT + b0 + r;               // value output
      if (isf) ((float*)outv)[oi] = s; else ((unsigned short*)outv)[oi] = 0;
    }
  }
  __syncthreads();
  if (tid < ROWS) {
    float l0 = lgts[tid][0], l1 = lgts[tid][1], l2 = lgts[tid][2];
    float mx = fmaxf(l0, fmaxf(l1, l2));
    float e0 = __expf(l0 - mx), e1 = __expf(l1 - mx), e2 = __expf(l2 - mx);
    float inv = 1.f / (e0 + e1 + e2);
    int oi = (b0 + tid) * 3;
    ((float*)outv)[oi + 0] = e0 * inv;
    ((float*)outv)[oi + 1] = e1 * inv;
    ((float*)outv)[oi + 2] = e2 * inv;
  }
}

extern "C" void kernel_launch(void* const* d_in, const int* in_sizes, int n_in,
                              void* d_out, int out_size, void* d_ws, size_t ws_size,
                              hipStream_t stream) {
  const void* x   = d_in[0];
  const void* Wc  = d_in[1];
  const void* bc  = d_in[2];
  const void* Wa1 = d_in[3];
  const void* ba1 = d_in[4];
  const void* Wa2 = d_in[5];
  const void* ba2 = d_in[6];
  const void* Wv1 = d_in[7];
  const void* bv1 = d_in[8];
  const void* Wv2 = d_in[9];
  const void* bv2 = d_in[10];

  int*   flag = (int*)d_ws;
  uint4* W0p  = (uint4*)((char*)d_ws + WP0_OFF);   // 640 KB digit-0 plane
  uint4* W1p  = (uint4*)((char*)d_ws + WP1_OFF);   // 640 KB scaled digit-1 plane

  detect_dtype<<<1, 64, 0, stream>>>((const unsigned short*)x, flag);
  repack_wc<<<160, 256, 0, stream>>>(Wc, W0p, W1p, flag);
  xlstm_main<<<NBLK, THREADS, 0, stream>>>(x, bc, W0p, W1p,
                                           Wa1, ba1, Wa2, ba2,
                                           Wv1, bv1, Wv2, bv2, d_out, flag);
}